// Round 3
// baseline (195.325 us; speedup 1.0000x reference)
//
#include <hip/hip_runtime.h>
#include <math.h>

#define FEAT 4096
#define BATCH 4096

// One block per row. 12 float4 loads pinned in-flight via sched_barrier ->
// 12 KB outstanding per wave (vs ~2 KB when the compiler serializes).
// Block computes relu(2 - ||o1-o3|| + ||o1-o2||) * BATCH and atomically adds
// to the scalar output (broadcast-sum semantics of the reference).
__global__ __launch_bounds__(256) void fused_loss_kernel(
    const float* __restrict__ o1, const float* __restrict__ o2,
    const float* __restrict__ o3, float* __restrict__ out)
{
    const int row = blockIdx.x;
    const int tid = threadIdx.x;
    const float4* p1 = (const float4*)(o1 + (size_t)row * FEAT);
    const float4* p2 = (const float4*)(o2 + (size_t)row * FEAT);
    const float4* p3 = (const float4*)(o3 + (size_t)row * FEAT);

    // Issue all 12 independent loads (16 B/lane, coalesced).
    float4 a0 = p1[tid];
    float4 a1 = p1[tid + 256];
    float4 a2 = p1[tid + 512];
    float4 a3 = p1[tid + 768];
    float4 c0 = p3[tid];
    float4 c1 = p3[tid + 256];
    float4 c2 = p3[tid + 512];
    float4 c3 = p3[tid + 768];
    float4 b0 = p2[tid];
    float4 b1 = p2[tid + 256];
    float4 b2 = p2[tid + 512];
    float4 b3 = p2[tid + 768];

    // Hard scheduling fence: nothing below may be hoisted above, and the
    // loads above may not be sunk below. Keeps all 12 loads in flight.
    __builtin_amdgcn_sched_barrier(0);

    float s13 = 0.0f, s12 = 0.0f;
    float d;
    // s13 uses a,c (ready first); s12 uses a,b (b loads complete last).
    d = a0.x - c0.x; s13 += d * d;  d = a0.y - c0.y; s13 += d * d;
    d = a0.z - c0.z; s13 += d * d;  d = a0.w - c0.w; s13 += d * d;
    d = a1.x - c1.x; s13 += d * d;  d = a1.y - c1.y; s13 += d * d;
    d = a1.z - c1.z; s13 += d * d;  d = a1.w - c1.w; s13 += d * d;
    d = a2.x - c2.x; s13 += d * d;  d = a2.y - c2.y; s13 += d * d;
    d = a2.z - c2.z; s13 += d * d;  d = a2.w - c2.w; s13 += d * d;
    d = a3.x - c3.x; s13 += d * d;  d = a3.y - c3.y; s13 += d * d;
    d = a3.z - c3.z; s13 += d * d;  d = a3.w - c3.w; s13 += d * d;

    d = a0.x - b0.x; s12 += d * d;  d = a0.y - b0.y; s12 += d * d;
    d = a0.z - b0.z; s12 += d * d;  d = a0.w - b0.w; s12 += d * d;
    d = a1.x - b1.x; s12 += d * d;  d = a1.y - b1.y; s12 += d * d;
    d = a1.z - b1.z; s12 += d * d;  d = a1.w - b1.w; s12 += d * d;
    d = a2.x - b2.x; s12 += d * d;  d = a2.y - b2.y; s12 += d * d;
    d = a2.z - b2.z; s12 += d * d;  d = a2.w - b2.w; s12 += d * d;
    d = a3.x - b3.x; s12 += d * d;  d = a3.y - b3.y; s12 += d * d;
    d = a3.z - b3.z; s12 += d * d;  d = a3.w - b3.w; s12 += d * d;

    // wave(64)-level butterfly reduce
    #pragma unroll
    for (int off = 32; off > 0; off >>= 1) {
        s13 += __shfl_down(s13, off, 64);
        s12 += __shfl_down(s12, off, 64);
    }

    __shared__ float ls13[4];
    __shared__ float ls12[4];
    const int wave = tid >> 6;
    const int lane = tid & 63;
    if (lane == 0) { ls13[wave] = s13; ls12[wave] = s12; }
    __syncthreads();
    if (tid == 0) {
        const float t13 = ls13[0] + ls13[1] + ls13[2] + ls13[3];
        const float t12 = ls12[0] + ls12[1] + ls12[2] + ls12[3];
        const float compare = 2.0f - sqrtf(t13) + sqrtf(t12);
        const float v = fmaxf(compare, 0.0f) * (float)BATCH;
        atomicAdd(out, v);   // 4096 adds to one address; device-scope default
    }
}

extern "C" void kernel_launch(void* const* d_in, const int* in_sizes, int n_in,
                              void* d_out, int out_size, void* d_ws, size_t ws_size,
                              hipStream_t stream) {
    const float* o1 = (const float*)d_in[0];
    const float* o2 = (const float*)d_in[1];
    const float* o3 = (const float*)d_in[2];
    float* out = (float*)d_out;  // single fp32 scalar

    hipMemsetAsync(out, 0, sizeof(float) * out_size, stream);
    fused_loss_kernel<<<BATCH, 256, 0, stream>>>(o1, o2, o3, out);
}

// Round 4
// 194.577 us; speedup vs baseline: 1.0038x; 1.0038x over previous
//
#include <hip/hip_runtime.h>
#include <math.h>

#define FEAT 4096
#define BATCH 4096

typedef __attribute__((address_space(1))) const void* gas_ptr;
typedef __attribute__((address_space(3))) void* las_ptr;

// One block per row. Async DMA (global_load_lds, 16 B/lane) stages all
// 3x16 KB rows into LDS with NO destination VGPRs -> all 12 wave-level
// staging instructions are in flight simultaneously (12 KB/wave outstanding,
// the compiler cannot serialize them). Then compute from LDS.
// Block computes relu(2 - ||o1-o3|| + ||o1-o2||) * BATCH and atomically
// adds to the scalar output (broadcast-sum semantics of the reference).
__global__ __launch_bounds__(256) void fused_loss_kernel(
    const float* __restrict__ o1, const float* __restrict__ o2,
    const float* __restrict__ o3, float* __restrict__ out)
{
    __shared__ __align__(16) float ldsA[FEAT];   // 16 KB
    __shared__ __align__(16) float ldsB[FEAT];   // 16 KB
    __shared__ __align__(16) float ldsC[FEAT];   // 16 KB
    __shared__ float red13[4];
    __shared__ float red12[4];

    const int row  = blockIdx.x;
    const int tid  = threadIdx.x;
    const int wave = tid >> 6;
    const int lane = tid & 63;

    const float* r1 = o1 + (size_t)row * FEAT;
    const float* r2 = o2 + (size_t)row * FEAT;
    const float* r3 = o3 + (size_t)row * FEAT;

    // Stage: wave w, chunk k covers float4 indices [(w*4+k)*64 + lane].
    // LDS dest = uniform base + lane*16 (hardware-applied), matching the
    // contiguous global layout.
    #pragma unroll
    for (int k = 0; k < 4; ++k) {
        const int f4 = (wave * 4 + k) * 64;   // float4 index of chunk base
        const int fl = f4 * 4;                // float index of chunk base
        __builtin_amdgcn_global_load_lds((gas_ptr)(r1 + fl + lane * 4),
                                         (las_ptr)(ldsA + fl), 16, 0, 0);
        __builtin_amdgcn_global_load_lds((gas_ptr)(r2 + fl + lane * 4),
                                         (las_ptr)(ldsB + fl), 16, 0, 0);
        __builtin_amdgcn_global_load_lds((gas_ptr)(r3 + fl + lane * 4),
                                         (las_ptr)(ldsC + fl), 16, 0, 0);
    }
    __builtin_amdgcn_s_waitcnt(0);   // drain vmcnt: all DMA landed in LDS
    __syncthreads();

    // Compute from LDS: thread t handles float4 indices t, t+256, t+512, t+768.
    const float4* A4 = (const float4*)ldsA;
    const float4* B4 = (const float4*)ldsB;
    const float4* C4 = (const float4*)ldsC;

    float s13 = 0.0f, s12 = 0.0f;
    #pragma unroll
    for (int k = 0; k < 4; ++k) {
        const int idx = tid + 256 * k;
        const float4 a = A4[idx];
        const float4 b = B4[idx];
        const float4 c = C4[idx];
        float d;
        d = a.x - c.x; s13 += d * d;  d = a.y - c.y; s13 += d * d;
        d = a.z - c.z; s13 += d * d;  d = a.w - c.w; s13 += d * d;
        d = a.x - b.x; s12 += d * d;  d = a.y - b.y; s12 += d * d;
        d = a.z - b.z; s12 += d * d;  d = a.w - b.w; s12 += d * d;
    }

    // wave(64)-level butterfly reduce
    #pragma unroll
    for (int off = 32; off > 0; off >>= 1) {
        s13 += __shfl_down(s13, off, 64);
        s12 += __shfl_down(s12, off, 64);
    }

    if (lane == 0) { red13[wave] = s13; red12[wave] = s12; }
    __syncthreads();
    if (tid == 0) {
        const float t13 = red13[0] + red13[1] + red13[2] + red13[3];
        const float t12 = red12[0] + red12[1] + red12[2] + red12[3];
        const float compare = 2.0f - sqrtf(t13) + sqrtf(t12);
        const float v = fmaxf(compare, 0.0f) * (float)BATCH;
        atomicAdd(out, v);   // 4096 adds to one address; device-scope default
    }
}

extern "C" void kernel_launch(void* const* d_in, const int* in_sizes, int n_in,
                              void* d_out, int out_size, void* d_ws, size_t ws_size,
                              hipStream_t stream) {
    const float* o1 = (const float*)d_in[0];
    const float* o2 = (const float*)d_in[1];
    const float* o3 = (const float*)d_in[2];
    float* out = (float*)d_out;  // single fp32 scalar

    hipMemsetAsync(out, 0, sizeof(float) * out_size, stream);
    fused_loss_kernel<<<BATCH, 256, 0, stream>>>(o1, o2, o3, out);
}